// Round 8
// baseline (1914.602 us; speedup 1.0000x reference)
//
#include <hip/hip_runtime.h>
#include <hip/hip_fp16.h>

// Problem constants
#define BB 128
#define SS 512
#define EE 16
#define HH 256
#define G3 768
#define VV 256

typedef _Float16 half8 __attribute__((ext_vector_type(8)));
typedef _Float16 half4_t __attribute__((ext_vector_type(4)));
typedef float f32x4 __attribute__((ext_vector_type(4)));

// ---------------------------------------------------------------------------
// P: swizzle W_hh [256][768] and W_out [256][256] (fp32, row=K, col=N) into
// fp16 MFMA B-fragment order: flat idx = ((n_tile*8 + k_tile)*64 + lane)*8 + j
//   = n*4096 + k*512 + L*8 + j
// holding W[k_tile*32 + (lane>>4)*8 + j][n_tile*16 + (lane&15)].
// ---------------------------------------------------------------------------
__global__ __launch_bounds__(256) void swizzle_weights(
    const float* __restrict__ Whh, const float* __restrict__ Wout,
    _Float16* __restrict__ whh_swz, _Float16* __restrict__ wout_swz) {
  int t = blockIdx.x * 256 + threadIdx.x;
  if (t < 48 * 8 * 64 * 8) {  // 196608 elements of W_hh
    int j = t & 7, L = (t >> 3) & 63, k = (t >> 9) & 7, n = t >> 12;
    int row = k * 32 + (L >> 4) * 8 + j;
    int col = n * 16 + (L & 15);
    whh_swz[t] = (_Float16)Whh[row * G3 + col];
  }
  if (t < 16 * 8 * 64 * 8) {  // 65536 elements of W_out
    int j = t & 7, L = (t >> 3) & 63, k = (t >> 9) & 7, n = t >> 12;
    int row = k * 32 + (L >> 4) * 8 + j;
    int col = n * 16 + (L & 15);
    wout_swz[t] = (_Float16)Wout[row * VV + col];
  }
}

// ---------------------------------------------------------------------------
// K1: gi = emb[x] @ W_ih + b_ih (+ b_hh folded for r,z gates), written fp16 in
// the swizzled per-(batch-group, t) layout K2's lanes read with 8B loads.
// 1024 blocks; each block handles 4 timesteps for one batch group, amortizing
// the 48 KB W_ih LDS staging 4x.  Static LDS = 48 + 3 + 4 KB = 55 KB.
// ---------------------------------------------------------------------------
__global__ __launch_bounds__(256) void gi_kernel(
    const int* __restrict__ x, const float* __restrict__ embed,
    const float* __restrict__ W_ih, const float* __restrict__ b_ih,
    const float* __restrict__ b_hh, _Float16* __restrict__ gi_swz) {
  int gid = blockIdx.x;          // 0..1023
  int bg = gid >> 7;             // batch group 0..7
  int t0 = (gid & 127) * 4;      // 4 timesteps per block
  int tid = threadIdx.x;

  __shared__ __align__(16) float s_wih[EE * G3];      // 48 KB
  __shared__ __align__(16) float s_bias[G3];          // 3 KB
  __shared__ __align__(16) float s_emb16[4][16][EE];  // 4 KB
  __shared__ int s_x[4][16];

  for (int i = tid; i < EE * G3; i += 256) s_wih[i] = W_ih[i];
  for (int i = tid; i < G3; i += 256)
    s_bias[i] = b_ih[i] + (i < 512 ? b_hh[i] : 0.0f);  // fold b_hh for r,z only
  if (tid < 64) {
    int tt = tid >> 4, m = tid & 15;
    s_x[tt][m] = x[(bg * 16 + m) * SS + t0 + tt];
  }
  __syncthreads();
  for (int i = tid; i < 4 * 16 * EE; i += 256) {
    int tt = i >> 8, m = (i >> 4) & 15, e = i & 15;
    s_emb16[tt][m][e] = embed[s_x[tt][m] * EE + e];
  }
  __syncthreads();

  for (int cch = 0; cch < 3; cch++) {
    int gc = cch * 256 + tid;  // gate column
    float w[EE];
#pragma unroll
    for (int e = 0; e < EE; e++) w[e] = s_wih[e * G3 + gc];
    float bias = s_bias[gc];
    int wi = (gc >> 4) & 15, cc = gc & 15;
    int tilebase = (cch * 16 + wi) * 64;
    for (int tt = 0; tt < 4; tt++) {
      size_t gbase = (size_t)(bg * 512 + t0 + tt) * 12288;
#pragma unroll
      for (int mq = 0; mq < 4; mq++) {
        half4_t v;
#pragma unroll
        for (int r = 0; r < 4; r++) {
          int m = mq * 4 + r;
          float acc = bias;
#pragma unroll
          for (int e = 0; e < EE; e++) acc += s_emb16[tt][m][e] * w[e];
          v[r] = (_Float16)acc;
        }
        *(half4_t*)(gi_swz + gbase + (size_t)((tilebase + mq * 16 + cc) * 4)) = v;
      }
    }
  }
}

// ---------------------------------------------------------------------------
// K2: GRU recurrence. 8 blocks x 512 threads (8 waves); block bg owns batch
// rows [bg*16, bg*16+16). Wave w (0..7) owns h-columns [w*32, w*32+32):
// TWO N-tiles per gate -> 48 B-fragments (192 VGPRs) per lane, and each LDS
// A-fragment read feeds 6 MFMAs (R7 structure: 3) -> LDS read traffic per
// step halves (64 ds_read_b128/CU).  waves_per_eu(2,2): 2 waves/SIMD ->
// 256-reg unified budget so all weights stay resident (R5-R7 spilled at
// 64/128-reg budgets: VALUBusy/CU ~70%, 6470 cy/step vs ~2300 model).
// Static LDS = 16.9 KB (double-buffered fp16 h tile, 264-pad).
// ---------------------------------------------------------------------------
__global__ void __launch_bounds__(512)
__attribute__((amdgpu_waves_per_eu(2, 2)))
gru_kernel(
    const _Float16* __restrict__ gi_swz, const _Float16* __restrict__ whh_swz,
    const float* __restrict__ b_hh, _Float16* __restrict__ h_seq) {
  int bg = blockIdx.x;  // 0..7
  int tid = threadIdx.x;
  int w = tid >> 6, L = tid & 63;  // w in 0..7
  int q = L >> 4, c = L & 15;

  __shared__ __align__(16) _Float16 s_h[2][16][264];  // 16.9 KB

  // All six B fragments x 8 k-steps for this wave's 32 columns (192 VGPRs).
  half8 wf[3][2][8];  // [gate][subtile][k]
#pragma unroll
  for (int g = 0; g < 3; g++)
#pragma unroll
    for (int i = 0; i < 2; i++) {
      int np = g * 16 + 2 * w + i;
#pragma unroll
      for (int k = 0; k < 8; k++)
        wf[g][i][k] = *(const half8*)(whh_swz + (((size_t)(np * 8 + k) * 64 + L) * 8));
    }
  // n-gate hidden bias (multiplied by r inside the step)
  float bhn0 = b_hh[512 + w * 32 + c];
  float bhn1 = b_hh[512 + w * 32 + 16 + c];

  // zero both h buffers (h0 = 0): 8448 halves = 4224 uints
  for (int idx = tid; idx < (2 * 16 * 264) / 2; idx += 512)
    ((unsigned int*)s_h)[idx] = 0u;
  __syncthreads();

  int col0 = w * 32 + c;
  // h_seq flat offset for (batch row bg*16 + q*4, t=0, col0); +HH per step
  unsigned hoff = (unsigned)(bg * 16 + q * 4) * (SS * HH) + (unsigned)col0;
  // gi base offset for this lane (gate g at +g*4096, subtile i at +i*256)
  unsigned gioff = (unsigned)(bg * 512) * 12288u + (unsigned)(w * 512 + L * 4);

  int cur = 0;
#pragma unroll 1
  for (int t = 0; t < SS; t++) {
    // gate-input loads (global, L2/L3-hot; issued early, consumed in epilogue)
    half4_t giR0 = *(const half4_t*)(gi_swz + gioff);
    half4_t giR1 = *(const half4_t*)(gi_swz + gioff + 256u);
    half4_t giZ0 = *(const half4_t*)(gi_swz + gioff + 4096u);
    half4_t giZ1 = *(const half4_t*)(gi_swz + gioff + 4352u);
    half4_t giN0 = *(const half4_t*)(gi_swz + gioff + 8192u);
    half4_t giN1 = *(const half4_t*)(gi_swz + gioff + 8448u);

    const _Float16* hsrc = &s_h[cur][0][0];
    // lane's own h_{t-1} values (C-layout positions), fp16
    half4_t hp0, hp1;
#pragma unroll
    for (int r = 0; r < 4; r++) {
      hp0[r] = hsrc[(q * 4 + r) * 264 + col0];
      hp1[r] = hsrc[(q * 4 + r) * 264 + col0 + 16];
    }

    f32x4 aR0 = {0.f, 0.f, 0.f, 0.f}, aR1 = aR0, aZ0 = aR0, aZ1 = aR0, aN0 = aR0, aN1 = aR0;
#pragma unroll
    for (int k = 0; k < 8; k++) {
      half8 av = *(const half8*)(hsrc + c * 264 + k * 32 + q * 8);  // A[m=c][k*32+q*8+j]
      aR0 = __builtin_amdgcn_mfma_f32_16x16x32_f16(av, wf[0][0][k], aR0, 0, 0, 0);
      aR1 = __builtin_amdgcn_mfma_f32_16x16x32_f16(av, wf[0][1][k], aR1, 0, 0, 0);
      aZ0 = __builtin_amdgcn_mfma_f32_16x16x32_f16(av, wf[1][0][k], aZ0, 0, 0, 0);
      aZ1 = __builtin_amdgcn_mfma_f32_16x16x32_f16(av, wf[1][1][k], aZ1, 0, 0, 0);
      aN0 = __builtin_amdgcn_mfma_f32_16x16x32_f16(av, wf[2][0][k], aN0, 0, 0, 0);
      aN1 = __builtin_amdgcn_mfma_f32_16x16x32_f16(av, wf[2][1][k], aN1, 0, 0, 0);
    }

    _Float16* hdst = &s_h[cur ^ 1][0][0];
#pragma unroll
    for (int r = 0; r < 4; r++) {
      int m = q * 4 + r;  // C/D row = (lane>>4)*4 + reg
      {  // subtile 0 (col0)
        float rg = aR0[r] + (float)giR0[r];
        rg = 1.f / (1.f + __expf(-rg));
        float zg = aZ0[r] + (float)giZ0[r];
        zg = 1.f / (1.f + __expf(-zg));
        float ng = (float)giN0[r] + rg * (aN0[r] + bhn0);
        ng = 2.f / (1.f + __expf(-2.f * ng)) - 1.f;  // tanh
        float hn = (1.f - zg) * ng + zg * (float)hp0[r];
        hdst[m * 264 + col0] = (_Float16)hn;
        h_seq[(size_t)hoff + (unsigned)r * (SS * HH)] = (_Float16)hn;
      }
      {  // subtile 1 (col0 + 16)
        float rg = aR1[r] + (float)giR1[r];
        rg = 1.f / (1.f + __expf(-rg));
        float zg = aZ1[r] + (float)giZ1[r];
        zg = 1.f / (1.f + __expf(-zg));
        float ng = (float)giN1[r] + rg * (aN1[r] + bhn1);
        ng = 2.f / (1.f + __expf(-2.f * ng)) - 1.f;  // tanh
        float hn = (1.f - zg) * ng + zg * (float)hp1[r];
        hdst[m * 264 + col0 + 16] = (_Float16)hn;
        h_seq[(size_t)hoff + (unsigned)r * (SS * HH) + 16u] = (_Float16)hn;
      }
    }
    __syncthreads();
    cur ^= 1;
    hoff += HH;
    gioff += 12288u;
  }
}

// ---------------------------------------------------------------------------
// K3: out = h_seq @ W_out + b_out via fp16 MFMA. 1024 blocks x 256 threads;
// block handles 64 bt-rows (wave w -> rows w*16..+16), full N=256 (16 tiles).
// Static LDS = 33 KB.  Output written fp32.
// ---------------------------------------------------------------------------
__global__ __launch_bounds__(256) void out_kernel(
    const _Float16* __restrict__ h_seq, const _Float16* __restrict__ wout_swz,
    const float* __restrict__ b_out, float* __restrict__ out) {
  int blk = blockIdx.x;
  int tid = threadIdx.x;
  int w = tid >> 6, L = tid & 63, q = L >> 4, c = L & 15;

  __shared__ __align__(16) _Float16 s_a[64 * 264];  // 33 KB

  const _Float16* src = h_seq + (size_t)blk * 64 * 256;
  for (int idx = tid; idx < (64 * 256) / 8; idx += 256) {
    int row = idx >> 5, kk = (idx & 31) * 8;
    *(half8*)(s_a + row * 264 + kk) = *(const half8*)(src + row * 256 + kk);
  }
  __syncthreads();

  half8 a[8];
#pragma unroll
  for (int k = 0; k < 8; k++)
    a[k] = *(const half8*)(s_a + (w * 16 + c) * 264 + k * 32 + q * 8);

  f32x4 acc[16];
#pragma unroll
  for (int n = 0; n < 16; n++) {
    f32x4 z = {0.f, 0.f, 0.f, 0.f};
    acc[n] = z;
#pragma unroll
    for (int k = 0; k < 8; k++) {
      half8 b = *(const half8*)(wout_swz + ((size_t)(n * 8 + k) * 64 + L) * 8);
      acc[n] = __builtin_amdgcn_mfma_f32_16x16x32_f16(a[k], b, acc[n], 0, 0, 0);
    }
  }
#pragma unroll
  for (int n = 0; n < 16; n++) {
    int v = n * 16 + c;
    float bo = b_out[v];
#pragma unroll
    for (int r = 0; r < 4; r++) {
      int bt = blk * 64 + w * 16 + q * 4 + r;
      out[(size_t)bt * 256 + v] = acc[n][r] + bo;
    }
  }
}

// ---------------------------------------------------------------------------
extern "C" void kernel_launch(void* const* d_in, const int* in_sizes, int n_in,
                              void* d_out, int out_size, void* d_ws, size_t ws_size,
                              hipStream_t stream) {
  const int*   x    = (const int*)d_in[0];
  const float* emb  = (const float*)d_in[1];
  const float* Wih  = (const float*)d_in[2];
  const float* bih  = (const float*)d_in[3];
  const float* Whh  = (const float*)d_in[4];
  const float* bhh  = (const float*)d_in[5];
  const float* Wout = (const float*)d_in[6];
  const float* bout = (const float*)d_in[7];

  char* ws = (char*)d_ws;
  // ws layout (134,742,016 B total):
  //   gi_swz   : 128*512*768 fp16 = 100,663,296 B
  //   whh_swz  : 196608 fp16      =     393,216 B
  //   wout_swz : 65536 fp16       =     131,072 B
  //   h_seq    : 128*512*256 fp16 =  33,554,432 B
  _Float16* gi_swz   = (_Float16*)(ws);
  _Float16* whh_swz  = (_Float16*)(ws + 100663296);
  _Float16* wout_swz = (_Float16*)(ws + 100663296 + 393216);
  _Float16* h_seq    = (_Float16*)(ws + 100663296 + 393216 + 131072);

  swizzle_weights<<<768, 256, 0, stream>>>(Whh, Wout, whh_swz, wout_swz);
  gi_kernel<<<1024, 256, 0, stream>>>(x, emb, Wih, bih, bhh, gi_swz);
  gru_kernel<<<8, 512, 0, stream>>>(gi_swz, whh_swz, bhh, h_seq);
  out_kernel<<<1024, 256, 0, stream>>>(h_seq, wout_swz, bout, (float*)d_out);
}

// Round 9
// 1596.102 us; speedup vs baseline: 1.1995x; 1.1995x over previous
//
#include <hip/hip_runtime.h>
#include <hip/hip_fp16.h>

// Problem constants
#define BB 128
#define SS 512
#define EE 16
#define HH 256
#define G3 768
#define VV 256

typedef _Float16 half8 __attribute__((ext_vector_type(8)));
typedef _Float16 half4_t __attribute__((ext_vector_type(4)));
typedef float f32x4 __attribute__((ext_vector_type(4)));

// ---------------------------------------------------------------------------
// P: swizzle W_hh [256][768] and W_out [256][256] (fp32, row=K, col=N) into
// fp16 MFMA B-fragment order: flat idx = ((n_tile*8 + k_tile)*64 + lane)*8 + j
//   = n*4096 + k*512 + L*8 + j
// holding W[k_tile*32 + (lane>>4)*8 + j][n_tile*16 + (lane&15)].
// ---------------------------------------------------------------------------
__global__ __launch_bounds__(256) void swizzle_weights(
    const float* __restrict__ Whh, const float* __restrict__ Wout,
    _Float16* __restrict__ whh_swz, _Float16* __restrict__ wout_swz) {
  int t = blockIdx.x * 256 + threadIdx.x;
  if (t < 48 * 8 * 64 * 8) {  // 196608 elements of W_hh
    int j = t & 7, L = (t >> 3) & 63, k = (t >> 9) & 7, n = t >> 12;
    int row = k * 32 + (L >> 4) * 8 + j;
    int col = n * 16 + (L & 15);
    whh_swz[t] = (_Float16)Whh[row * G3 + col];
  }
  if (t < 16 * 8 * 64 * 8) {  // 65536 elements of W_out
    int j = t & 7, L = (t >> 3) & 63, k = (t >> 9) & 7, n = t >> 12;
    int row = k * 32 + (L >> 4) * 8 + j;
    int col = n * 16 + (L & 15);
    wout_swz[t] = (_Float16)Wout[row * VV + col];
  }
}

// ---------------------------------------------------------------------------
// K1: gi = emb[x] @ W_ih + b_ih (+ b_hh folded for r,z gates), written fp16 in
// the swizzled per-(batch-group, t) layout K2's lanes read with 8B loads.
// 1024 blocks; each block handles 4 timesteps for one batch group, amortizing
// the 48 KB W_ih LDS staging 4x.  Static LDS = 48 + 3 + 4 KB = 55 KB.
// ---------------------------------------------------------------------------
__global__ __launch_bounds__(256) void gi_kernel(
    const int* __restrict__ x, const float* __restrict__ embed,
    const float* __restrict__ W_ih, const float* __restrict__ b_ih,
    const float* __restrict__ b_hh, _Float16* __restrict__ gi_swz) {
  int gid = blockIdx.x;          // 0..1023
  int bg = gid >> 7;             // batch group 0..7
  int t0 = (gid & 127) * 4;      // 4 timesteps per block
  int tid = threadIdx.x;

  __shared__ __align__(16) float s_wih[EE * G3];      // 48 KB
  __shared__ __align__(16) float s_bias[G3];          // 3 KB
  __shared__ __align__(16) float s_emb16[4][16][EE];  // 4 KB
  __shared__ int s_x[4][16];

  for (int i = tid; i < EE * G3; i += 256) s_wih[i] = W_ih[i];
  for (int i = tid; i < G3; i += 256)
    s_bias[i] = b_ih[i] + (i < 512 ? b_hh[i] : 0.0f);  // fold b_hh for r,z only
  if (tid < 64) {
    int tt = tid >> 4, m = tid & 15;
    s_x[tt][m] = x[(bg * 16 + m) * SS + t0 + tt];
  }
  __syncthreads();
  for (int i = tid; i < 4 * 16 * EE; i += 256) {
    int tt = i >> 8, m = (i >> 4) & 15, e = i & 15;
    s_emb16[tt][m][e] = embed[s_x[tt][m] * EE + e];
  }
  __syncthreads();

  for (int cch = 0; cch < 3; cch++) {
    int gc = cch * 256 + tid;  // gate column
    float w[EE];
#pragma unroll
    for (int e = 0; e < EE; e++) w[e] = s_wih[e * G3 + gc];
    float bias = s_bias[gc];
    int wi = (gc >> 4) & 15, cc = gc & 15;
    int tilebase = (cch * 16 + wi) * 64;
    for (int tt = 0; tt < 4; tt++) {
      size_t gbase = (size_t)(bg * 512 + t0 + tt) * 12288;
#pragma unroll
      for (int mq = 0; mq < 4; mq++) {
        half4_t v;
#pragma unroll
        for (int r = 0; r < 4; r++) {
          int m = mq * 4 + r;
          float acc = bias;
#pragma unroll
          for (int e = 0; e < EE; e++) acc += s_emb16[tt][m][e] * w[e];
          v[r] = (_Float16)acc;
        }
        *(half4_t*)(gi_swz + gbase + (size_t)((tilebase + mq * 16 + cc) * 4)) = v;
      }
    }
  }
}

// ---------------------------------------------------------------------------
// K2: GRU recurrence. 8 blocks x 1024 threads (16 waves, 4/SIMD -- R8 showed
// 2/SIMD starves latency hiding). Wave w owns h-columns [w*16, w*16+16): one
// N-tile per gate => 24 B-fragments (96 regs/lane). waves_per_eu(4,4): 128-reg
// unified budget.
// Register diet vs R7 (R7: VALUBusy/CU 69% => ~480 spill-copy insts/wave/step,
// weights lived in AGPRs with per-MFMA v_accvgpr_read):
//  - aR/aZ accumulators init directly from gi (gi regs die pre-MFMA);
//    aN stays 0-init because n_i is NOT multiplied by r; giN loads post-MFMA.
//  - hp (h_{t-1}) read post-MFMA.
//  - t-loop unrolled x2 (static ping-pong, no 'cur').
// MFMA-block working set ~= 96 w + 12 acc + ~15 transient <= 128.
// Static LDS = 16.9 KB (double-buffered fp16 h tile, 264-pad).
// ---------------------------------------------------------------------------
__global__ void __launch_bounds__(1024)
__attribute__((amdgpu_waves_per_eu(4, 4)))
gru_kernel(
    const _Float16* __restrict__ gi_swz, const _Float16* __restrict__ whh_swz,
    const float* __restrict__ b_hh, _Float16* __restrict__ h_seq) {
  int bg = blockIdx.x;  // 0..7
  int tid = threadIdx.x;
  int w = tid >> 6, L = tid & 63;
  int q = L >> 4, c = L & 15;

  __shared__ __align__(16) _Float16 s_h[2][16][264];  // 16.9 KB

  // All three B fragments for this wave's column tile, in registers (96 regs).
  half8 wR[8], wZ[8], wN[8];
#pragma unroll
  for (int k = 0; k < 8; k++) {
    wR[k] = *(const half8*)(whh_swz + (((size_t)((0 * 16 + w) * 8 + k) * 64 + L) * 8));
    wZ[k] = *(const half8*)(whh_swz + (((size_t)((1 * 16 + w) * 8 + k) * 64 + L) * 8));
    wN[k] = *(const half8*)(whh_swz + (((size_t)((2 * 16 + w) * 8 + k) * 64 + L) * 8));
  }
  // n-gate hidden bias (multiplied by r inside the step)
  float bhn = b_hh[512 + w * 16 + c];

  // zero both h buffers (h0 = 0): 8448 halves = 4224 uints
  for (int idx = tid; idx < (2 * 16 * 264) / 2; idx += 1024)
    ((unsigned int*)s_h)[idx] = 0u;
  __syncthreads();

  int col = w * 16 + c;
  // h_seq flat offset for (batch row bg*16 + q*4, t=0, col); advance by HH/step
  unsigned hoff = (unsigned)(bg * 16 + q * 4) * (SS * HH) + (unsigned)col;
  // gi base offset for this lane (advance by 12288/step)
  unsigned gioff = (unsigned)(bg * 512) * 12288u + (unsigned)((w * 64 + L) * 4);

  auto step = [&](const _Float16* hsrc, _Float16* hdst) {
    // r,z accumulators initialized from gate inputs (gi regs die here)
    f32x4 aR, aZ, aN = {0.f, 0.f, 0.f, 0.f};
    {
      half4_t giR = *(const half4_t*)(gi_swz + gioff);
      half4_t giZ = *(const half4_t*)(gi_swz + gioff + 4096u);
#pragma unroll
      for (int r = 0; r < 4; r++) { aR[r] = (float)giR[r]; aZ[r] = (float)giZ[r]; }
    }
#pragma unroll
    for (int k = 0; k < 8; k++) {
      half8 av = *(const half8*)(hsrc + c * 264 + k * 32 + q * 8);  // A[m=c][k*32+q*8+j]
      aR = __builtin_amdgcn_mfma_f32_16x16x32_f16(av, wR[k], aR, 0, 0, 0);
      aZ = __builtin_amdgcn_mfma_f32_16x16x32_f16(av, wZ[k], aZ, 0, 0, 0);
      aN = __builtin_amdgcn_mfma_f32_16x16x32_f16(av, wN[k], aN, 0, 0, 0);
    }
    // n-gate inputs + previous h, loaded only now (post-MFMA, short-lived)
    half4_t giN = *(const half4_t*)(gi_swz + gioff + 8192u);
#pragma unroll
    for (int r = 0; r < 4; r++) {
      int m = q * 4 + r;  // C/D row = (lane>>4)*4 + reg
      float hp = (float)hsrc[m * 264 + col];
      float rg = 1.f / (1.f + __expf(-aR[r]));
      float zg = 1.f / (1.f + __expf(-aZ[r]));
      float ng = (float)giN[r] + rg * (aN[r] + bhn);
      ng = 2.f / (1.f + __expf(-2.f * ng)) - 1.f;  // tanh
      float hn = (1.f - zg) * ng + zg * hp;
      hdst[m * 264 + col] = (_Float16)hn;
      h_seq[(size_t)hoff + (unsigned)r * (SS * HH)] = (_Float16)hn;
    }
    __syncthreads();
    hoff += HH;
    gioff += 12288u;
  };

#pragma unroll 1
  for (int t = 0; t < SS; t += 2) {
    step(&s_h[0][0][0], &s_h[1][0][0]);
    step(&s_h[1][0][0], &s_h[0][0][0]);
  }
}

// ---------------------------------------------------------------------------
// K3: out = h_seq @ W_out + b_out via fp16 MFMA. 1024 blocks x 256 threads;
// block handles 64 bt-rows (wave w -> rows w*16..+16), full N=256 (16 tiles).
// Static LDS = 33 KB.  Output written fp32.
// ---------------------------------------------------------------------------
__global__ __launch_bounds__(256) void out_kernel(
    const _Float16* __restrict__ h_seq, const _Float16* __restrict__ wout_swz,
    const float* __restrict__ b_out, float* __restrict__ out) {
  int blk = blockIdx.x;
  int tid = threadIdx.x;
  int w = tid >> 6, L = tid & 63, q = L >> 4, c = L & 15;

  __shared__ __align__(16) _Float16 s_a[64 * 264];  // 33 KB

  const _Float16* src = h_seq + (size_t)blk * 64 * 256;
  for (int idx = tid; idx < (64 * 256) / 8; idx += 256) {
    int row = idx >> 5, kk = (idx & 31) * 8;
    *(half8*)(s_a + row * 264 + kk) = *(const half8*)(src + row * 256 + kk);
  }
  __syncthreads();

  half8 a[8];
#pragma unroll
  for (int k = 0; k < 8; k++)
    a[k] = *(const half8*)(s_a + (w * 16 + c) * 264 + k * 32 + q * 8);

  f32x4 acc[16];
#pragma unroll
  for (int n = 0; n < 16; n++) {
    f32x4 z = {0.f, 0.f, 0.f, 0.f};
    acc[n] = z;
#pragma unroll
    for (int k = 0; k < 8; k++) {
      half8 b = *(const half8*)(wout_swz + ((size_t)(n * 8 + k) * 64 + L) * 8);
      acc[n] = __builtin_amdgcn_mfma_f32_16x16x32_f16(a[k], b, acc[n], 0, 0, 0);
    }
  }
#pragma unroll
  for (int n = 0; n < 16; n++) {
    int v = n * 16 + c;
    float bo = b_out[v];
#pragma unroll
    for (int r = 0; r < 4; r++) {
      int bt = blk * 64 + w * 16 + q * 4 + r;
      out[(size_t)bt * 256 + v] = acc[n][r] + bo;
    }
  }
}

// ---------------------------------------------------------------------------
extern "C" void kernel_launch(void* const* d_in, const int* in_sizes, int n_in,
                              void* d_out, int out_size, void* d_ws, size_t ws_size,
                              hipStream_t stream) {
  const int*   x    = (const int*)d_in[0];
  const float* emb  = (const float*)d_in[1];
  const float* Wih  = (const float*)d_in[2];
  const float* bih  = (const float*)d_in[3];
  const float* Whh  = (const float*)d_in[4];
  const float* bhh  = (const float*)d_in[5];
  const float* Wout = (const float*)d_in[6];
  const float* bout = (const float*)d_in[7];

  char* ws = (char*)d_ws;
  // ws layout (134,742,016 B total):
  //   gi_swz   : 128*512*768 fp16 = 100,663,296 B
  //   whh_swz  : 196608 fp16      =     393,216 B
  //   wout_swz : 65536 fp16       =     131,072 B
  //   h_seq    : 128*512*256 fp16 =  33,554,432 B
  _Float16* gi_swz   = (_Float16*)(ws);
  _Float16* whh_swz  = (_Float16*)(ws + 100663296);
  _Float16* wout_swz = (_Float16*)(ws + 100663296 + 393216);
  _Float16* h_seq    = (_Float16*)(ws + 100663296 + 393216 + 131072);

  swizzle_weights<<<768, 256, 0, stream>>>(Whh, Wout, whh_swz, wout_swz);
  gi_kernel<<<1024, 256, 0, stream>>>(x, emb, Wih, bih, bhh, gi_swz);
  gru_kernel<<<8, 1024, 0, stream>>>(gi_swz, whh_swz, bhh, h_seq);
  out_kernel<<<1024, 256, 0, stream>>>(h_seq, wout_swz, bout, (float*)d_out);
}